// Round 4
// baseline (422.540 us; speedup 1.0000x reference)
//
#include <hip/hip_runtime.h>
#include <math.h>

#define M_LEN 40000
#define B_SZ 16
#define K_TAPS 201
#define T_HALF 100
#define L_OUT 39800          // M_LEN - K_TAPS + 1
#define TL 256               // outputs per block
#define NTILES 156           // ceil(L_OUT / TL)
#define NP 456               // TL + K_TAPS - 1
#define NPS 458              // NP + 2 : staged series positions (A/B need +s)
#define NPX 460              // NP + 4 : x positions
#define STR 464              // series stride (floats), mult of 4
#define NSER 20

// window element t in 0..6: t<4 -> P component, else C component
__device__ __forceinline__ float gw(const float4 P, const float4 C, int t) {
    switch (t) {
        case 0: return P.x; case 1: return P.y; case 2: return P.z; case 3: return P.w;
        case 4: return C.x; case 5: return C.y; case 6: return C.z; default: return C.w;
    }
}

// 4 taps x 4 outputs, real weights
__device__ __forceinline__ void conv4r(const float4 P, const float4 C,
                                       const float* w, float* acc) {
#pragma unroll
    for (int jj = 0; jj < 4; ++jj)
#pragma unroll
        for (int o = 0; o < 4; ++o)
            acc[o] = fmaf(w[jj], gw(P, C, jj + o), acc[o]);
}

// complex series window feeding TWO convs: plus-rule (w*V) and minus-rule (w*conj(V))
__device__ __forceinline__ void conv4c2(const float4 Pr, const float4 Cr,
                                        const float4 Pi, const float4 Ci,
                                        const float* wpr, const float* wpi,
                                        float* apr, float* api,
                                        const float* wnr, const float* wni,
                                        float* anr, float* ani) {
#pragma unroll
    for (int jj = 0; jj < 4; ++jj)
#pragma unroll
        for (int o = 0; o < 4; ++o) {
            float vr = gw(Pr, Cr, jj + o);
            float vi = gw(Pi, Ci, jj + o);
            apr[o] = fmaf(wpr[jj], vr, fmaf(-wpi[jj], vi, apr[o]));
            api[o] = fmaf(wpr[jj], vi, fmaf( wpi[jj], vr, api[o]));
            anr[o] = fmaf(wnr[jj], vr, fmaf( wni[jj], vi, anr[o]));
            ani[o] = fmaf(wni[jj], vr, fmaf(-wnr[jj], vi, ani[o]));
        }
}

// plus-rule only:  acc += w * V
__device__ __forceinline__ void conv4p(const float4 Pr, const float4 Cr,
                                       const float4 Pi, const float4 Ci,
                                       const float* wr, const float* wi,
                                       float* ar, float* ai) {
#pragma unroll
    for (int jj = 0; jj < 4; ++jj)
#pragma unroll
        for (int o = 0; o < 4; ++o) {
            float vr = gw(Pr, Cr, jj + o);
            float vi = gw(Pi, Ci, jj + o);
            ar[o] = fmaf(wr[jj], vr, fmaf(-wi[jj], vi, ar[o]));
            ai[o] = fmaf(wr[jj], vi, fmaf( wi[jj], vr, ai[o]));
        }
}

// minus-rule only: acc += w * conj(V)
__device__ __forceinline__ void conv4n(const float4 Pr, const float4 Cr,
                                       const float4 Pi, const float4 Ci,
                                       const float* wr, const float* wi,
                                       float* ar, float* ai) {
#pragma unroll
    for (int jj = 0; jj < 4; ++jj)
#pragma unroll
        for (int o = 0; o < 4; ++o) {
            float vr = gw(Pr, Cr, jj + o);
            float vi = gw(Pi, Ci, jj + o);
            ar[o] = fmaf(wr[jj], vr, fmaf( wi[jj], vi, ar[o]));
            ai[o] = fmaf(wi[jj], vr, fmaf(-wr[jj], vi, ai[o]));
        }
}

__global__ __launch_bounds__(128, 2) void snse_kernel(
    const float* __restrict__ g_xr, const float* __restrict__ g_xi,
    const float* __restrict__ g_ti, const float* __restrict__ g_c00,
    const float* __restrict__ g_wx, const float* __restrict__ g_wc,
    const float* __restrict__ g_wr, const float* __restrict__ g_wi,
    float* __restrict__ g_out)
{
    // series: 0 ps0, 1 ps1, 2 qr, 3 qi; sg in {0,1} (shift s = sg+1):
    // base=4+8*sg: +0 Ar0 +1 Ar1 +2 Ai0 +3 Ai1 +4 Br0 +5 Br1 +6 Bi0 +7 Bi1
    __shared__ __align__(16) float S[NSER * STR];           // 37120 B
    __shared__ _Float16 s_xr_h[2][STR], s_xi_h[2][STR];     //  3712 B

    const int tid = threadIdx.x;
    const int b   = blockIdx.y;
    const int l0  = blockIdx.x * TL;

    const float tdb    = g_ti[b * 4 + 0];
    const float P      = expf(tdb * 0.23025850929940457f) * 0.5f; // 10^(t/10)/2
    const float sP     = sqrtf(P);
    const float inv_sP = 1.0f / sP;
    const float C00    = g_c00[0];

    // ---- stage scaled x (f16): positions m = l0-2 .. l0+NPX-3 (mod M) ----
    for (int idx = tid; idx < 2 * NPX; idx += 128) {
        int pidx = idx >> 1, ch = idx & 1;
        int m = l0 - 2 + pidx;
        int mw = m < 0 ? m + M_LEN : (m >= M_LEN ? m - M_LEN : m);
        int g = (b * M_LEN + mw) * 2 + ch;
        s_xr_h[ch][pidx] = (_Float16)(g_xr[g] * sP);
        s_xi_h[ch][pidx] = (_Float16)(g_xi[g] * sP);
    }
    __syncthreads();

    // ---- stage series for ALL positions idx = 0..STR-1 ----
    // idx < NPS: real series (m = l0 + idx); idx >= NPS: ZERO-FILL pad.
    // The tap loop's zero-weighted window reads touch idx up to STR-1;
    // uninitialized LDS there would inject NaN (0 * NaN = NaN).
    for (int idx = tid; idx < STR; idx += 128) {
        if (idx < NPS) {
            const int ix = idx + 2;
            float x0r = (float)s_xr_h[0][ix], x0i = (float)s_xi_h[0][ix];
            float x1r = (float)s_xr_h[1][ix], x1i = (float)s_xi_h[1][ix];
            float p0 = x0r * x0r + x0i * x0i;
            float p1 = x1r * x1r + x1i * x1i;
            S[0 * STR + idx] = 2.f * p0 + p1;
            S[1 * STR + idx] = 2.f * p1 + p0;
            S[2 * STR + idx] = x0r * x1r + x0i * x1i;   // qr
            S[3 * STR + idx] = x0i * x1r - x0r * x1i;   // qi
#pragma unroll
            for (int sg = 0; sg < 2; ++sg) {
                const int s = sg + 1;
                const int jx = ix - s;                  // x[m - s]
                float a0r = (float)s_xr_h[0][jx], a0i = (float)s_xi_h[0][jx];
                float a1r = (float)s_xr_h[1][jx], a1i = (float)s_xi_h[1][jx];
                float U0r = x0r * a0r + x0i * a0i;
                float U0i = x0i * a0r - x0r * a0i;
                float U1r = x1r * a1r + x1i * a1i;
                float U1i = x1i * a1r - x1r * a1i;
                const int ba = 4 + sg * 8;
                S[(ba + 0) * STR + idx] = 2.f * U0r + U1r;
                S[(ba + 1) * STR + idx] = 2.f * U1r + U0r;
                S[(ba + 2) * STR + idx] = 2.f * U0i + U1i;
                S[(ba + 3) * STR + idx] = 2.f * U1i + U0i;
                S[(ba + 4) * STR + idx] = x0r * a1r + x0i * a1i;  // Br0
                S[(ba + 5) * STR + idx] = x1r * a0r + x1i * a0i;  // Br1
                S[(ba + 6) * STR + idx] = x0i * a1r - x0r * a1i;  // Bi0
                S[(ba + 7) * STR + idx] = x1i * a0r - x1r * a0i;  // Bi1
            }
        } else {
#pragma unroll
            for (int a = 0; a < NSER; ++a)
                S[a * STR + idx] = 0.f;
        }
    }
    __syncthreads();

    // ---- main conv loop: thread owns outputs l0+4g..l0+4g+3, channel nn ----
    const int g  = tid & 63;
    const int nn = tid >> 6;
    const int r  = g << 2;

    float acc_ix[4] = {0.f, 0.f, 0.f, 0.f};
    float acc_qr[4] = {0.f, 0.f, 0.f, 0.f};
    float acc_qi[4] = {0.f, 0.f, 0.f, 0.f};
    float fAr[4][4] = {}; // [si][o], si: 0=-2, 1=-1, 2=+1, 3=+2
    float fAi[4][4] = {};
    float fBr[4][4] = {};
    float fBi[4][4] = {};

    const int a_ps = nn * STR + r;
    const int a_qr = 2 * STR + r;
    const int a_qi = 3 * STR + r;
    int aAr[2], aAi[2], aBor[2], aBoi[2], aBxr[2], aBxi[2];
#pragma unroll
    for (int sg = 0; sg < 2; ++sg) {
        const int ba = 4 + sg * 8;
        aAr[sg]  = (ba + 0 + nn) * STR + r;        // A re, own ch
        aAi[sg]  = (ba + 2 + nn) * STR + r;        // A im, own ch
        aBor[sg] = (ba + 4 + nn) * STR + r;        // B re, own ch  (+s conv)
        aBoi[sg] = (ba + 6 + nn) * STR + r;
        aBxr[sg] = (ba + 4 + (1 - nn)) * STR + r;  // B re, other ch (-s conv)
        aBxi[sg] = (ba + 6 + (1 - nn)) * STR + r;
    }

    float4 P_ps = *(const float4*)&S[a_ps];
    float4 P_qr = *(const float4*)&S[a_qr];
    float4 P_qi = *(const float4*)&S[a_qi];
    float4 PAr[2], PAi[2], PBor[2], PBoi[2], PBxr[2], PBxi[2];
#pragma unroll
    for (int sg = 0; sg < 2; ++sg) {
        PAr[sg]  = *(const float4*)&S[aAr[sg]];
        PAi[sg]  = *(const float4*)&S[aAi[sg]];
        PBor[sg] = *(const float4*)&S[aBor[sg]];
        PBoi[sg] = *(const float4*)&S[aBoi[sg]];
        PBxr[sg] = *(const float4*)&S[aBxr[sg]];
        PBxi[sg] = *(const float4*)&S[aBxi[sg]];
    }

#pragma unroll 1
    for (int bb = 0; bb < 26; ++bb) {
        const int j0 = bb * 8;
        // uniform guarded weights (zero-padded taps) -> scalar pipe
        float wxv[8], wcv[8], wPr[2][8], wPi[2][8], wNr[2][8], wNi[2][8];
#pragma unroll
        for (int jj = 0; jj < 8; ++jj) {
            const int t = j0 + jj;
            const bool v = (t <= 200);
            wxv[jj] = v ? g_wx[t] : 0.f;
            wcv[jj] = v ? g_wc[t] : 0.f;
#pragma unroll
            for (int sg = 0; sg < 2; ++sg) {
                const int sip = 2 + sg, sin_ = 1 - sg, s = sg + 1;
                wPr[sg][jj] = v ? g_wr[sip * K_TAPS + t] : 0.f;
                wPi[sg][jj] = v ? g_wi[sip * K_TAPS + t] : 0.f;
                const int tn = t - s;
                const bool vn = (tn >= 0) && (tn <= 200);
                wNr[sg][jj] = vn ? g_wr[sin_ * K_TAPS + tn] : 0.f;
                wNi[sg][jj] = vn ? g_wi[sin_ * K_TAPS + tn] : 0.f;
            }
        }
        // ps / q (real-weight convs)
        {
            float4 c  = *(const float4*)&S[a_ps + j0 + 4];
            conv4r(P_ps, c, &wxv[0], acc_ix);
            float4 c2 = *(const float4*)&S[a_ps + j0 + 8];
            conv4r(c, c2, &wxv[4], acc_ix);
            P_ps = c2;
        }
        {
            float4 c  = *(const float4*)&S[a_qr + j0 + 4];
            conv4r(P_qr, c, &wcv[0], acc_qr);
            float4 c2 = *(const float4*)&S[a_qr + j0 + 8];
            conv4r(c, c2, &wcv[4], acc_qr);
            P_qr = c2;
        }
        {
            float4 c  = *(const float4*)&S[a_qi + j0 + 4];
            conv4r(P_qi, c, &wcv[0], acc_qi);
            float4 c2 = *(const float4*)&S[a_qi + j0 + 8];
            conv4r(c, c2, &wcv[4], acc_qi);
            P_qi = c2;
        }
#pragma unroll
        for (int sg = 0; sg < 2; ++sg) {
            const int sip = 2 + sg, sin_ = 1 - sg;
            // A window: feeds fA[sip] (plus) and fA[sin_] (minus, conj+wshift)
            {
                float4 cr  = *(const float4*)&S[aAr[sg] + j0 + 4];
                float4 ci  = *(const float4*)&S[aAi[sg] + j0 + 4];
                conv4c2(PAr[sg], cr, PAi[sg], ci,
                        &wPr[sg][0], &wPi[sg][0], fAr[sip], fAi[sip],
                        &wNr[sg][0], &wNi[sg][0], fAr[sin_], fAi[sin_]);
                float4 cr2 = *(const float4*)&S[aAr[sg] + j0 + 8];
                float4 ci2 = *(const float4*)&S[aAi[sg] + j0 + 8];
                conv4c2(cr, cr2, ci, ci2,
                        &wPr[sg][4], &wPi[sg][4], fAr[sip], fAi[sip],
                        &wNr[sg][4], &wNi[sg][4], fAr[sin_], fAi[sin_]);
                PAr[sg] = cr2; PAi[sg] = ci2;
            }
            // B own-channel: feeds fB[sip] (plus)
            {
                float4 cr  = *(const float4*)&S[aBor[sg] + j0 + 4];
                float4 ci  = *(const float4*)&S[aBoi[sg] + j0 + 4];
                conv4p(PBor[sg], cr, PBoi[sg], ci,
                       &wPr[sg][0], &wPi[sg][0], fBr[sip], fBi[sip]);
                float4 cr2 = *(const float4*)&S[aBor[sg] + j0 + 8];
                float4 ci2 = *(const float4*)&S[aBoi[sg] + j0 + 8];
                conv4p(cr, cr2, ci, ci2,
                       &wPr[sg][4], &wPi[sg][4], fBr[sip], fBi[sip]);
                PBor[sg] = cr2; PBoi[sg] = ci2;
            }
            // B other-channel: feeds fB[sin_] (minus)
            {
                float4 cr  = *(const float4*)&S[aBxr[sg] + j0 + 4];
                float4 ci  = *(const float4*)&S[aBxi[sg] + j0 + 4];
                conv4n(PBxr[sg], cr, PBxi[sg], ci,
                       &wNr[sg][0], &wNi[sg][0], fBr[sin_], fBi[sin_]);
                float4 cr2 = *(const float4*)&S[aBxr[sg] + j0 + 8];
                float4 ci2 = *(const float4*)&S[aBxi[sg] + j0 + 8];
                conv4n(cr, cr2, ci, ci2,
                       &wNr[sg][4], &wNi[sg][4], fBr[sin_], fBi[sin_]);
                PBxr[sg] = cr2; PBxi[sg] = ci2;
            }
        }
    }

    // ---- zero-center-tap correction (zcv only) ----
    {
        const float wx100 = g_wx[T_HALF];
        const float wc100 = g_wc[T_HALF];
        float4 vps = *(const float4*)&S[a_ps + T_HALF];
        float4 vqr = *(const float4*)&S[a_qr + T_HALF];
        float4 vqi = *(const float4*)&S[a_qi + T_HALF];
#pragma unroll
        for (int o = 0; o < 4; ++o) {
            acc_ix[o] = fmaf(-wx100, gw(vps, vps, o), acc_ix[o]);
            acc_qr[o] = fmaf(-wc100, gw(vqr, vqr, o), acc_qr[o]);
            acc_qi[o] = fmaf(-wc100, gw(vqi, vqi, o), acc_qi[o]);
        }
    }

    // ---- epilogue ----
    const int ssf[4] = {-2, -1, 1, 2};
#pragma unroll
    for (int o = 0; o < 4; ++o) {
        const int lrel = r + o;
        const int l = l0 + lrel;
        const int xc = lrel + T_HALF + 2;
        float X0r = (float)s_xr_h[0][xc], X0i = (float)s_xi_h[0][xc];
        float X1r = (float)s_xr_h[1][xc], X1i = (float)s_xi_h[1][xc];
        float pw  = X0r * X0r + X0i * X0i + X1r * X1r + X1i * X1i;
        float phi = C00 * pw + 2.f * acc_ix[o];
        float sph, cph;
        __sincosf(phi, &sph, &cph);
        float qcr = acc_qr[o];
        float qci = nn ? -acc_qi[o] : acc_qi[o];
        float br_ = nn ? X1r : X0r, bi_ = nn ? X1i : X0i;
        float or_ = nn ? X0r : X1r, oi_ = nn ? X0i : X1i;
        float ici_r = -(or_ * qci + oi_ * qcr);
        float ici_i =   or_ * qcr - oi_ * qci;
        float fw_r = 0.f, fw_i = 0.f;
#pragma unroll
        for (int si = 0; si < 4; ++si) {
            int sx = xc - ssf[si];
            float xnr  = (float)s_xr_h[nn][sx],     xni = (float)s_xi_h[nn][sx];
            float xor_ = (float)s_xr_h[1 - nn][sx], xoi = (float)s_xi_h[1 - nn][sx];
            fw_r += xnr * fAr[si][o] - xni * fAi[si][o]
                  + xor_ * fBr[si][o] - xoi * fBi[si][o];
            fw_i += xnr * fAi[si][o] + xni * fAr[si][o]
                  + xor_ * fBi[si][o] + xoi * fBr[si][o];
        }
        float out_r = br_ * cph - bi_ * sph + ici_r + fw_r;
        float out_i = br_ * sph + bi_ * cph + ici_i + fw_i;
        if (l < L_OUT) {
            int oidx = (((b * L_OUT) + l) * 2 + nn) * 2;
            g_out[oidx]     = out_r * inv_sP;
            g_out[oidx + 1] = out_i * inv_sP;
        }
    }
}

extern "C" void kernel_launch(void* const* d_in, const int* in_sizes, int n_in,
                              void* d_out, int out_size, void* d_ws, size_t ws_size,
                              hipStream_t stream) {
    const float* xr  = (const float*)d_in[0];
    const float* xi  = (const float*)d_in[1];
    const float* ti  = (const float*)d_in[2];
    const float* c00 = (const float*)d_in[3];
    const float* wx  = (const float*)d_in[4];
    const float* wc  = (const float*)d_in[5];
    const float* wr  = (const float*)d_in[6];
    const float* wi  = (const float*)d_in[7];
    float* out = (float*)d_out;

    dim3 grid(NTILES, B_SZ, 1);
    dim3 block(128, 1, 1);
    snse_kernel<<<grid, block, 0, stream>>>(xr, xi, ti, c00, wx, wc, wr, wi, out);
}

// Round 6
// 244.371 us; speedup vs baseline: 1.7291x; 1.7291x over previous
//
#include <hip/hip_runtime.h>
#include <math.h>

#define M_LEN 40000
#define B_SZ 16
#define K_TAPS 201
#define T_HALF 100
#define L_OUT 39800          // M_LEN - K_TAPS + 1
#define TL 256               // outputs per block
#define NTILES 156           // ceil(L_OUT / TL)
#define NP 456               // TL + K_TAPS - 1
#define NPS 458              // NP + 2 : staged series positions
#define NPX 460              // NP + 4 : x positions
#define XSTR 464             // x f16 stride
#define PAIRS 240            // staged series pairs (max read index 231)
#define SSTR 242             // series pair-array stride in dwords (even!)
#define NSER 20
#define WPP 104              // weight pairs per array-version (208 taps)
#define NWARR 20             // 10 arrays x 2 versions

typedef unsigned int uint;
typedef __fp16 h2 __attribute__((ext_vector_type(2)));

static __device__ __forceinline__ h2 U2H(uint u){ h2 r; __builtin_memcpy(&r,&u,4); return r; }
static __device__ __forceinline__ uint H2U(h2 h){ uint r; __builtin_memcpy(&r,&h,4); return r; }

#define FDOT2(w,v,acc) (acc) = __builtin_amdgcn_fdot2((w),(v),(acc),false)
#define NEGW(u) ((u) ^ 0x80008000u)

// ---------------- prep kernel: pack padded/shifted f16 weight pairs into d_ws ---
// array a: 0 wx, 1 wc, 2 wPr0, 3 wPi0, 4 wNr0, 5 wNi0, 6 wPr1, 7 wPi1, 8 wNr1, 9 wNi1
// version 0: pair p = (w[2p], w[2p+1]); version 1: (w[2p-1], w[2p])  [w'[u]=w[u-1]]
static __device__ float wval(int a, int t, const float* wx, const float* wc,
                             const float* wr, const float* wi){
    if (a == 0) return (t >= 0 && t <= 200) ? wx[t] : 0.f;
    if (a == 1) return (t >= 0 && t <= 200) ? wc[t] : 0.f;
    int sg = (a >= 6) ? 1 : 0;
    int k  = a - (sg ? 6 : 2);       // 0 plusR, 1 plusI, 2 minusR, 3 minusI
    if (k < 2) {
        int row = 2 + sg;            // sip
        const float* s = (k == 0) ? wr : wi;
        return (t >= 0 && t <= 200) ? s[row * K_TAPS + t] : 0.f;
    } else {
        int row = 1 - sg;            // sin_
        int sh  = sg + 1;            // tap shift s
        const float* s = (k == 2) ? wr : wi;
        int tt = t - sh;
        return (tt >= 0 && tt <= 200) ? s[row * K_TAPS + tt] : 0.f;
    }
}

__global__ void prep_weights(const float* __restrict__ wx, const float* __restrict__ wc,
                             const float* __restrict__ wr, const float* __restrict__ wi,
                             uint* __restrict__ W) {
    int idx = blockIdx.x * 256 + threadIdx.x;
    if (idx >= NWARR * WPP) return;
    int p   = idx % WPP;
    int av  = idx / WPP;
    int ver = av & 1;
    int a   = av >> 1;
    int t0  = 2 * p - ver;
    float f0 = wval(a, t0,     wx, wc, wr, wi);
    float f1 = wval(a, t0 + 1, wx, wc, wr, wi);
    W[idx] = H2U(__builtin_amdgcn_cvt_pkrtz(f0, f1));
}

// ---------------- main kernel helpers -----------------------------------------
struct Win10 { h2 hp[10]; };

// window pairs rel 8k .. 8k+9 : carried c = pairs (8k, 8k+1); loads 4 uint2; c <- last
static __device__ __forceinline__ Win10 loadwin(const uint* base, int ko, uint2& c) {
    Win10 w;
    uint2 u1 = *(const uint2*)(base + ko + 2);
    uint2 u2 = *(const uint2*)(base + ko + 4);
    uint2 u3 = *(const uint2*)(base + ko + 6);
    uint2 u4 = *(const uint2*)(base + ko + 8);
    w.hp[0] = U2H(c.x);  w.hp[1] = U2H(c.y);
    w.hp[2] = U2H(u1.x); w.hp[3] = U2H(u1.y);
    w.hp[4] = U2H(u2.x); w.hp[5] = U2H(u2.y);
    w.hp[6] = U2H(u3.x); w.hp[7] = U2H(u3.y);
    w.hp[8] = U2H(u4.x); w.hp[9] = U2H(u4.y);
    c = u4;
    return w;
}

// real conv: 4 outputs, 8 tap-pairs. w0 = even-o weights, w1 = shifted (odd-o)
static __device__ __forceinline__ void dotr(const Win10& W, const uint* w0, const uint* w1,
                                            float* acc) {
#pragma unroll
    for (int P = 0; P < 8; ++P) {
        FDOT2(U2H(w0[P]), W.hp[P],     acc[0]);
        FDOT2(U2H(w1[P]), W.hp[P],     acc[1]);
        FDOT2(U2H(w0[P]), W.hp[P + 1], acc[2]);
        FDOT2(U2H(w1[P]), W.hp[P + 1], acc[3]);
    }
}

// complex window feeding plus-rule (w*V) and minus-rule (w*conj(V)) accumulators
static __device__ __forceinline__ void dotc2(const Win10& R, const Win10& I,
        const uint* pr0, const uint* pr1, const uint* pi0, const uint* pi1,
        const uint* nr0, const uint* nr1, const uint* ni0, const uint* ni1,
        float* pR, float* pI, float* nR, float* nI) {
#pragma unroll
    for (int P = 0; P < 8; ++P) {
#pragma unroll
        for (int oi = 0; oi < 4; ++oi) {
            const uint* wpr = (oi & 1) ? pr1 : pr0;
            const uint* wpi = (oi & 1) ? pi1 : pi0;
            const uint* wnr = (oi & 1) ? nr1 : nr0;
            const uint* wni = (oi & 1) ? ni1 : ni0;
            const int off = P + (oi >> 1);
            FDOT2(U2H(wpr[P]),       R.hp[off], pR[oi]);
            FDOT2(U2H(NEGW(wpi[P])), I.hp[off], pR[oi]);
            FDOT2(U2H(wpi[P]),       R.hp[off], pI[oi]);
            FDOT2(U2H(wpr[P]),       I.hp[off], pI[oi]);
            FDOT2(U2H(wnr[P]),       R.hp[off], nR[oi]);
            FDOT2(U2H(wni[P]),       I.hp[off], nR[oi]);
            FDOT2(U2H(wni[P]),       R.hp[off], nI[oi]);
            FDOT2(U2H(NEGW(wnr[P])), I.hp[off], nI[oi]);
        }
    }
}

static __device__ __forceinline__ void dotp(const Win10& R, const Win10& I,
        const uint* pr0, const uint* pr1, const uint* pi0, const uint* pi1,
        float* pR, float* pI) {
#pragma unroll
    for (int P = 0; P < 8; ++P) {
#pragma unroll
        for (int oi = 0; oi < 4; ++oi) {
            const uint* wpr = (oi & 1) ? pr1 : pr0;
            const uint* wpi = (oi & 1) ? pi1 : pi0;
            const int off = P + (oi >> 1);
            FDOT2(U2H(wpr[P]),       R.hp[off], pR[oi]);
            FDOT2(U2H(NEGW(wpi[P])), I.hp[off], pR[oi]);
            FDOT2(U2H(wpi[P]),       R.hp[off], pI[oi]);
            FDOT2(U2H(wpr[P]),       I.hp[off], pI[oi]);
        }
    }
}

static __device__ __forceinline__ void dotn(const Win10& R, const Win10& I,
        const uint* nr0, const uint* nr1, const uint* ni0, const uint* ni1,
        float* nR, float* nI) {
#pragma unroll
    for (int P = 0; P < 8; ++P) {
#pragma unroll
        for (int oi = 0; oi < 4; ++oi) {
            const uint* wnr = (oi & 1) ? nr1 : nr0;
            const uint* wni = (oi & 1) ? ni1 : ni0;
            const int off = P + (oi >> 1);
            FDOT2(U2H(wnr[P]),       R.hp[off], nR[oi]);
            FDOT2(U2H(wni[P]),       I.hp[off], nR[oi]);
            FDOT2(U2H(wni[P]),       R.hp[off], nI[oi]);
            FDOT2(U2H(NEGW(wnr[P])), I.hp[off], nI[oi]);
        }
    }
}

static __device__ __forceinline__ void calc_series(
        const _Float16 (*sxr)[XSTR], const _Float16 (*sxi)[XSTR], int pos, float* v) {
    const int ix = pos + 2;
    float x0r = (float)sxr[0][ix], x0i = (float)sxi[0][ix];
    float x1r = (float)sxr[1][ix], x1i = (float)sxi[1][ix];
    float p0 = x0r * x0r + x0i * x0i;
    float p1 = x1r * x1r + x1i * x1i;
    v[0] = 2.f * p0 + p1;
    v[1] = 2.f * p1 + p0;
    v[2] = x0r * x1r + x0i * x1i;       // qr
    v[3] = x0i * x1r - x0r * x1i;       // qi
#pragma unroll
    for (int sg = 0; sg < 2; ++sg) {
        const int jx = ix - (sg + 1);
        float a0r = (float)sxr[0][jx], a0i = (float)sxi[0][jx];
        float a1r = (float)sxr[1][jx], a1i = (float)sxi[1][jx];
        float U0r = x0r * a0r + x0i * a0i;
        float U0i = x0i * a0r - x0r * a0i;
        float U1r = x1r * a1r + x1i * a1i;
        float U1i = x1i * a1r - x1r * a1i;
        const int ba = 4 + sg * 8;
        v[ba + 0] = 2.f * U0r + U1r;
        v[ba + 1] = 2.f * U1r + U0r;
        v[ba + 2] = 2.f * U0i + U1i;
        v[ba + 3] = 2.f * U1i + U0i;
        v[ba + 4] = x0r * a1r + x0i * a1i;  // Br0
        v[ba + 5] = x1r * a0r + x1i * a0i;  // Br1
        v[ba + 6] = x0i * a1r - x0r * a1i;  // Bi0
        v[ba + 7] = x1i * a0r - x1r * a0i;  // Bi1
    }
}

__global__ __launch_bounds__(128, 3) void snse_kernel(
    const float* __restrict__ g_xr, const float* __restrict__ g_xi,
    const float* __restrict__ g_ti, const float* __restrict__ g_c00,
    const float* __restrict__ g_wx, const float* __restrict__ g_wc,
    const uint* __restrict__ Wg,   // packed f16 weight pairs from prep kernel
    float* __restrict__ g_out)
{
    // series: 0 ps0, 1 ps1, 2 qr, 3 qi; sg: base=4+8sg: +0 Ar0 +1 Ar1 +2 Ai0 +3 Ai1
    //                                                    +4 Br0 +5 Br1 +6 Bi0 +7 Bi1
    __shared__ __align__(16) uint SE[NSER * SSTR];              // 19360 B
    __shared__ _Float16 s_xr_h[2][XSTR], s_xi_h[2][XSTR];       //  3712 B

    const int tid = threadIdx.x;
    const int b   = blockIdx.y;
    const int l0  = blockIdx.x * TL;

    const float tdb    = g_ti[b * 4 + 0];
    const float P      = expf(tdb * 0.23025850929940457f) * 0.5f; // 10^(t/10)/2
    const float sP     = sqrtf(P);
    const float inv_sP = 1.0f / sP;
    const float C00    = g_c00[0];

    // ---- stage scaled x (f16): positions m = l0-2 .. l0+NPX-3 (mod M) ----
    for (int idx = tid; idx < 2 * NPX; idx += 128) {
        int pidx = idx >> 1, ch = idx & 1;
        int m = l0 - 2 + pidx;
        int mw = m < 0 ? m + M_LEN : (m >= M_LEN ? m - M_LEN : m);
        int gg = (b * M_LEN + mw) * 2 + ch;
        s_xr_h[ch][pidx] = (_Float16)(g_xr[gg] * sP);
        s_xi_h[ch][pidx] = (_Float16)(g_xi[gg] * sP);
    }
    __syncthreads();

    // ---- stage packed f16 series pairs; zero-fill beyond NPS (NaN guard!) ----
    for (int p = tid; p < PAIRS; p += 128) {
        float v0[NSER], v1[NSER];
#pragma unroll
        for (int a = 0; a < NSER; ++a) { v0[a] = 0.f; v1[a] = 0.f; }
        const int m0 = 2 * p, m1 = 2 * p + 1;
        if (m0 < NPS) calc_series(s_xr_h, s_xi_h, m0, v0);
        if (m1 < NPS) calc_series(s_xr_h, s_xi_h, m1, v1);
#pragma unroll
        for (int a = 0; a < NSER; ++a)
            SE[a * SSTR + p] = H2U(__builtin_amdgcn_cvt_pkrtz(v0[a], v1[a]));
    }
    __syncthreads();

    // ---- main conv loop: thread owns outputs l0+4g..+3, channel nn ----
    const int g  = tid & 63;
    const int nn = tid >> 6;
    const int r  = g << 2;
    const int pb = g << 1;          // pair-index base = r/2

    float acc_ix[4] = {}, acc_qr[4] = {}, acc_qi[4] = {};
    float fAr[4][4] = {}, fAi[4][4] = {}, fBr[4][4] = {}, fBi[4][4] = {};

    const uint* bps = &SE[nn * SSTR + pb];
    const uint* bqr = &SE[2 * SSTR + pb];
    const uint* bqi = &SE[3 * SSTR + pb];
    const uint *bAr[2], *bAi[2], *bBor[2], *bBoi[2], *bBxr[2], *bBxi[2];
#pragma unroll
    for (int sg = 0; sg < 2; ++sg) {
        const int ba = 4 + sg * 8;
        bAr[sg]  = &SE[(ba + 0 + nn) * SSTR + pb];
        bAi[sg]  = &SE[(ba + 2 + nn) * SSTR + pb];
        bBor[sg] = &SE[(ba + 4 + nn) * SSTR + pb];
        bBoi[sg] = &SE[(ba + 6 + nn) * SSTR + pb];
        bBxr[sg] = &SE[(ba + 4 + (1 - nn)) * SSTR + pb];
        bBxi[sg] = &SE[(ba + 6 + (1 - nn)) * SSTR + pb];
    }

    uint2 cps = *(const uint2*)bps;
    uint2 cqr = *(const uint2*)bqr;
    uint2 cqi = *(const uint2*)bqi;
    uint2 cAr[2], cAi[2], cBor[2], cBoi[2], cBxr[2], cBxi[2];
#pragma unroll
    for (int sg = 0; sg < 2; ++sg) {
        cAr[sg]  = *(const uint2*)bAr[sg];
        cAi[sg]  = *(const uint2*)bAi[sg];
        cBor[sg] = *(const uint2*)bBor[sg];
        cBoi[sg] = *(const uint2*)bBoi[sg];
        cBxr[sg] = *(const uint2*)bBxr[sg];
        cBxi[sg] = *(const uint2*)bBxi[sg];
    }

#pragma unroll 1
    for (int k = 0; k < 13; ++k) {
        const int ko = k * 8;
        // weight-pair pointers for this 16-tap block (uniform -> s_load)
        const uint* WX0 = Wg + (0 * 2 + 0) * WPP + ko;
        const uint* WX1 = Wg + (0 * 2 + 1) * WPP + ko;
        const uint* WC0 = Wg + (1 * 2 + 0) * WPP + ko;
        const uint* WC1 = Wg + (1 * 2 + 1) * WPP + ko;

        { Win10 w = loadwin(bps, ko, cps); dotr(w, WX0, WX1, acc_ix); }
        { Win10 w = loadwin(bqr, ko, cqr); dotr(w, WC0, WC1, acc_qr); }
        { Win10 w = loadwin(bqi, ko, cqi); dotr(w, WC0, WC1, acc_qi); }

#pragma unroll
        for (int sg = 0; sg < 2; ++sg) {
            const int sip = 2 + sg, sin_ = 1 - sg;
            const int aPr = 2 + 4 * sg, aPi = 3 + 4 * sg, aNr = 4 + 4 * sg, aNi = 5 + 4 * sg;
            const uint* pr0 = Wg + (aPr * 2 + 0) * WPP + ko;
            const uint* pr1 = Wg + (aPr * 2 + 1) * WPP + ko;
            const uint* pi0 = Wg + (aPi * 2 + 0) * WPP + ko;
            const uint* pi1 = Wg + (aPi * 2 + 1) * WPP + ko;
            const uint* nr0 = Wg + (aNr * 2 + 0) * WPP + ko;
            const uint* nr1 = Wg + (aNr * 2 + 1) * WPP + ko;
            const uint* ni0 = Wg + (aNi * 2 + 0) * WPP + ko;
            const uint* ni1 = Wg + (aNi * 2 + 1) * WPP + ko;
            {
                Win10 R = loadwin(bAr[sg], ko, cAr[sg]);
                Win10 I = loadwin(bAi[sg], ko, cAi[sg]);
                dotc2(R, I, pr0, pr1, pi0, pi1, nr0, nr1, ni0, ni1,
                      fAr[sip], fAi[sip], fAr[sin_], fAi[sin_]);
            }
            {
                Win10 R = loadwin(bBor[sg], ko, cBor[sg]);
                Win10 I = loadwin(bBoi[sg], ko, cBoi[sg]);
                dotp(R, I, pr0, pr1, pi0, pi1, fBr[sip], fBi[sip]);
            }
            {
                Win10 R = loadwin(bBxr[sg], ko, cBxr[sg]);
                Win10 I = loadwin(bBxi[sg], ko, cBxi[sg]);
                dotn(R, I, nr0, nr1, ni0, ni1, fBr[sin_], fBi[sin_]);
            }
        }
    }

    // ---- zero-center-tap correction (zcv only); f16-rounded weights to match conv ----
    {
        const float wx100 = (float)(_Float16)g_wx[T_HALF];
        const float wc100 = (float)(_Float16)g_wc[T_HALF];
#pragma unroll
        for (int o = 0; o < 4; ++o) {
            const int pos = r + o + T_HALF;
            const int pp = pos >> 1, pe = pos & 1;
            h2 vps = U2H(SE[nn * SSTR + pp]);
            h2 vqr = U2H(SE[2 * SSTR + pp]);
            h2 vqi = U2H(SE[3 * SSTR + pp]);
            acc_ix[o] = fmaf(-wx100, (float)vps[pe], acc_ix[o]);
            acc_qr[o] = fmaf(-wc100, (float)vqr[pe], acc_qr[o]);
            acc_qi[o] = fmaf(-wc100, (float)vqi[pe], acc_qi[o]);
        }
    }

    // ---- epilogue ----
    const int ssf[4] = {-2, -1, 1, 2};
#pragma unroll
    for (int o = 0; o < 4; ++o) {
        const int lrel = r + o;
        const int l = l0 + lrel;
        const int xc = lrel + T_HALF + 2;
        float X0r = (float)s_xr_h[0][xc], X0i = (float)s_xi_h[0][xc];
        float X1r = (float)s_xr_h[1][xc], X1i = (float)s_xi_h[1][xc];
        float pw  = X0r * X0r + X0i * X0i + X1r * X1r + X1i * X1i;
        float phi = C00 * pw + 2.f * acc_ix[o];
        float sph, cph;
        __sincosf(phi, &sph, &cph);
        float qcr = acc_qr[o];
        float qci = nn ? -acc_qi[o] : acc_qi[o];
        float br_ = nn ? X1r : X0r, bi_ = nn ? X1i : X0i;
        float or_ = nn ? X0r : X1r, oi_ = nn ? X0i : X1i;
        float ici_r = -(or_ * qci + oi_ * qcr);
        float ici_i =   or_ * qcr - oi_ * qci;
        float fw_r = 0.f, fw_i = 0.f;
#pragma unroll
        for (int si = 0; si < 4; ++si) {
            int sx = xc - ssf[si];
            float xnr  = (float)s_xr_h[nn][sx],     xni = (float)s_xi_h[nn][sx];
            float xor_ = (float)s_xr_h[1 - nn][sx], xoi = (float)s_xi_h[1 - nn][sx];
            fw_r += xnr * fAr[si][o] - xni * fAi[si][o]
                  + xor_ * fBr[si][o] - xoi * fBi[si][o];
            fw_i += xnr * fAi[si][o] + xni * fAr[si][o]
                  + xor_ * fBi[si][o] + xoi * fBr[si][o];
        }
        float out_r = br_ * cph - bi_ * sph + ici_r + fw_r;
        float out_i = br_ * sph + bi_ * cph + ici_i + fw_i;
        if (l < L_OUT) {
            int oidx = (((b * L_OUT) + l) * 2 + nn) * 2;
            g_out[oidx]     = out_r * inv_sP;
            g_out[oidx + 1] = out_i * inv_sP;
        }
    }
}

extern "C" void kernel_launch(void* const* d_in, const int* in_sizes, int n_in,
                              void* d_out, int out_size, void* d_ws, size_t ws_size,
                              hipStream_t stream) {
    const float* xr  = (const float*)d_in[0];
    const float* xi  = (const float*)d_in[1];
    const float* ti  = (const float*)d_in[2];
    const float* c00 = (const float*)d_in[3];
    const float* wx  = (const float*)d_in[4];
    const float* wc  = (const float*)d_in[5];
    const float* wr  = (const float*)d_in[6];
    const float* wi  = (const float*)d_in[7];
    float* out = (float*)d_out;
    uint* W = (uint*)d_ws;   // NWARR*WPP*4 = 8320 bytes

    prep_weights<<<dim3((NWARR * WPP + 255) / 256), dim3(256), 0, stream>>>(wx, wc, wr, wi, W);

    dim3 grid(NTILES, B_SZ, 1);
    dim3 block(128, 1, 1);
    snse_kernel<<<grid, block, 0, stream>>>(xr, xi, ti, c00, wx, wc, W, out);
}